// Round 10
// baseline (217.468 us; speedup 1.0000x reference)
//
#include <hip/hip_runtime.h>

#define NHEADS 12
#define HDIM   64
#define EMB    768
#define SEQ    1024
#define BATCH  4
#define MTOT   (BATCH * SEQ)

typedef __bf16 bf16x8 __attribute__((ext_vector_type(8)));
typedef float  f32x4  __attribute__((ext_vector_type(4)));

#define GLB(p) ((const __attribute__((address_space(1))) uint32_t*)(p))
#define LDS(p) ((__attribute__((address_space(3))) uint32_t*)(p))
#define VMCNT(n) asm volatile("s_waitcnt vmcnt(" #n ")" ::: "memory")
#define LGKM0()  asm volatile("s_waitcnt lgkmcnt(0)" ::: "memory")

__device__ __forceinline__ uint bfr(float f) {  // f32 -> bf16 bits, RNE
    uint u = __float_as_uint(f);
    return (u + 0x7fffu + ((u >> 16) & 1u)) >> 16;
}

// ---------------------------------------------------------------------------
// One launch: split hs + 4 weights to bf16 hi/lo, and pack pos_row/col.
// ---------------------------------------------------------------------------
__global__ __launch_bounds__(256) void split_all(
    const float* __restrict__ hs,
    const float* __restrict__ w0, const float* __restrict__ w1,
    const float* __restrict__ w2, const float* __restrict__ w3,
    const int* __restrict__ pos_row, const int* __restrict__ pos_col,
    ushort* __restrict__ hsh, ushort* __restrict__ hsl,
    ushort* __restrict__ wch, ushort* __restrict__ wcl,
    ushort* __restrict__ woh, ushort* __restrict__ wol,
    int* __restrict__ pos_pk)
{
    const int bx = blockIdx.x;
    if (bx >= 5376) {
        int i = (bx - 5376) * 256 + threadIdx.x;
        pos_pk[i] = (pos_row[i] << 8) | pos_col[i];
        return;
    }
    const float* src;
    ushort *hi, *lo;
    int i;
    if (bx < 3072) {
        src = hs; hi = hsh; lo = hsl;
        i = bx * 256 + threadIdx.x;
    } else {
        const int y = (bx - 3072) / 576;
        const int r = (bx - 3072) - y * 576;
        src = (y == 0) ? w0 : (y == 1) ? w1 : (y == 2) ? w2 : w3;
        hi = (y < 3) ? (wch + (size_t)y * (EMB * EMB)) : woh;
        lo = (y < 3) ? (wcl + (size_t)y * (EMB * EMB)) : wol;
        i = r * 256 + threadIdx.x;
    }
    float4 v = ((const float4*)src)[i];
    float f[4] = {v.x, v.y, v.z, v.w};
    ushort hh[4], ll[4];
#pragma unroll
    for (int j = 0; j < 4; ++j) {
        uint h = bfr(f[j]);
        float hf = __uint_as_float(h << 16);
        ll[j] = (ushort)bfr(f[j] - hf);
        hh[j] = (ushort)h;
    }
    ushort4 hv = {hh[0], hh[1], hh[2], hh[3]};
    ushort4 lv = {ll[0], ll[1], ll[2], ll[3]};
    ((ushort4*)hi)[i] = hv;
    ((ushort4*)lo)[i] = lv;
}

// ---------------------------------------------------------------------------
// QKV GEMM: round-7 measured-best: 128x128 tile, BK=32, 8 waves of 64x32,
// counted-vmcnt 2-barrier schedule with lgkm pin before MFMA.
// ---------------------------------------------------------------------------
__global__ __launch_bounds__(512) void gemm_qkv(
    const ushort* __restrict__ Ah, const ushort* __restrict__ Al,
    const ushort* __restrict__ Wh, const ushort* __restrict__ Wl,
    const float* __restrict__ b0, const float* __restrict__ b1,
    const float* __restrict__ b2,
    ushort* __restrict__ q16, ushort* __restrict__ k16,
    ushort* __restrict__ vT16)
{
    constexpr int TS = 32768;  // [Ah 8K][Al 8K][Wh 8K][Wl 8K]
    __shared__ __align__(16) char ldsc[2 * TS];

    const int t  = threadIdx.x;
    const int w  = t >> 6;
    const int l  = t & 63;
    const int m0 = blockIdx.x * 128;
    const int n0 = blockIdx.y * 128;
    const int wm = w >> 2;   // 0..1
    const int wn = w & 3;    // 0..3

    const char* gb[4] = {
        (const char*)Ah + (size_t)m0 * 1536,
        (const char*)Al + (size_t)m0 * 1536,
        (const char*)Wh + (size_t)n0 * 1536,
        (const char*)Wl + (size_t)n0 * 1536};

    int aoff[4], boff[2];
#pragma unroll
    for (int i = 0; i < 4; ++i) {
        int row = wm * 64 + i * 16 + (l & 15);
        aoff[i] = row * 64 + ((((l >> 4) ^ ((row >> 1) & 3))) << 4);
    }
#pragma unroll
    for (int j = 0; j < 2; ++j) {
        int rn = wn * 32 + j * 16 + (l & 15);
        boff[j] = rn * 64 + ((((l >> 4) ^ ((rn >> 1) & 3))) << 4);
    }

    auto stage = [&](int ks, int buf) {
        const size_t kb = (size_t)ks * 64;
        char* dst = ldsc + buf * TS;
        const int soff = t * 16;
        const int srow = soff >> 6;
        const int slot = (soff >> 4) & 3;
        const size_t go = (size_t)srow * 1536 +
                          ((slot ^ ((srow >> 1) & 3)) << 4) + kb;
#pragma unroll
        for (int tt = 0; tt < 4; ++tt)
            __builtin_amdgcn_global_load_lds(GLB(gb[tt] + go),
                                             LDS(dst + tt * 8192 + soff), 16, 0, 0);
    };

    f32x4 acc[4][2] = {};

    stage(0, 0);

    for (int ks = 0; ks < 24; ++ks) {
        if (ks + 1 < 24) {
            stage(ks + 1, (ks + 1) & 1);
            VMCNT(4);
        } else {
            VMCNT(0);
        }
        __builtin_amdgcn_s_barrier();

        const char* cur = ldsc + (ks & 1) * TS;
        bf16x8 ah[4], al[4], bh[2], bl[2];
#pragma unroll
        for (int i = 0; i < 4; ++i) {
            ah[i] = *(const bf16x8*)(cur + aoff[i]);
            al[i] = *(const bf16x8*)(cur + 8192 + aoff[i]);
        }
#pragma unroll
        for (int j = 0; j < 2; ++j) {
            bh[j] = *(const bf16x8*)(cur + 16384 + boff[j]);
            bl[j] = *(const bf16x8*)(cur + 24576 + boff[j]);
        }
        LGKM0();
        __builtin_amdgcn_sched_barrier(0);
        __builtin_amdgcn_s_barrier();

        __builtin_amdgcn_s_setprio(1);
#pragma unroll
        for (int i = 0; i < 4; ++i)
#pragma unroll
            for (int j = 0; j < 2; ++j) {
                acc[i][j] = __builtin_amdgcn_mfma_f32_16x16x32_bf16(ah[i], bh[j], acc[i][j], 0, 0, 0);
                acc[i][j] = __builtin_amdgcn_mfma_f32_16x16x32_bf16(ah[i], bl[j], acc[i][j], 0, 0, 0);
                acc[i][j] = __builtin_amdgcn_mfma_f32_16x16x32_bf16(al[i], bh[j], acc[i][j], 0, 0, 0);
            }
        __builtin_amdgcn_s_setprio(0);
    }

    const int mrow_base = m0 + wm * 64 + ((l >> 4) << 2);
    const int which = (n0 >= 1536) ? 2 : (n0 >= 768 ? 1 : 0);
    const int nin_base = n0 - which * 768 + wn * 32 + (l & 15);

    if (which == 2) {
#pragma unroll
        for (int j = 0; j < 2; ++j) {
            const int n_in = nin_base + j * 16;
            const float bv = b2[n_in];
            const int h = n_in >> 6, d = n_in & 63;
#pragma unroll
            for (int i = 0; i < 4; ++i) {
                const int m = mrow_base + i * 16;
                const int bb = m >> 10, s = m & 1023;
                ushort4 pk = {(ushort)bfr(acc[i][j][0] + bv),
                              (ushort)bfr(acc[i][j][1] + bv),
                              (ushort)bfr(acc[i][j][2] + bv),
                              (ushort)bfr(acc[i][j][3] + bv)};
                *(ushort4*)(vT16 + (size_t)((bb * NHEADS + h) * HDIM + d) * SEQ + s) = pk;
            }
        }
    } else {
        ushort* op = (which == 0) ? q16 : k16;
        const float* bpt = (which == 0) ? b0 : b1;
        const float scale = (which == 0) ? 0.125f : 1.0f;
#pragma unroll
        for (int j = 0; j < 2; ++j) {
            const int n_in = nin_base + j * 16;
            const float bv = bpt[n_in];
            const int h = n_in >> 6, d = n_in & 63;
#pragma unroll
            for (int i = 0; i < 4; ++i)
#pragma unroll
                for (int r = 0; r < 4; ++r) {
                    const int m = mrow_base + i * 16 + r;
                    const int bb = m >> 10, s = m & 1023;
                    op[(size_t)((bb * NHEADS + h) * SEQ + s) * HDIM + d] =
                        (ushort)bfr((acc[i][j][r] + bv) * scale);
                }
        }
    }
}

// ---------------------------------------------------------------------------
// o-projection: BM=64 x BN=128, 4 waves of 32x64 (6 frag reads feed 24
// MFMAs = 256 B/MFMA), 48KB LDS -> 3 blocks/CU, counted-vmcnt schedule.
// ---------------------------------------------------------------------------
__global__ __launch_bounds__(256) void gemm_oproj(
    const ushort* __restrict__ Ah, const ushort* __restrict__ Al,
    const ushort* __restrict__ Wh, const ushort* __restrict__ Wl,
    const float* __restrict__ b0, float* __restrict__ o0)
{
    constexpr int SA = 4096;
    constexpr int SB = 8192;
    constexpr int TS = 2 * SA + 2 * SB;  // 24576
    __shared__ __align__(16) char ldsc[2 * TS];

    const int t  = threadIdx.x;
    const int w  = t >> 6;
    const int l  = t & 63;
    const int m0 = blockIdx.x * 64;
    const int n0 = blockIdx.y * 128;
    const int wm = w >> 1;   // 0..1, 32 rows
    const int wn = w & 1;    // 0..1, 64 cols

    const char* gb[4] = {
        (const char*)Ah + (size_t)m0 * 1536,
        (const char*)Al + (size_t)m0 * 1536,
        (const char*)Wh + (size_t)n0 * 1536,
        (const char*)Wl + (size_t)n0 * 1536};

    int aoff[2], boff[4];
#pragma unroll
    for (int i = 0; i < 2; ++i) {
        int row = wm * 32 + i * 16 + (l & 15);
        aoff[i] = row * 64 + ((((l >> 4) ^ ((row >> 1) & 3))) << 4);
    }
#pragma unroll
    for (int i = 0; i < 4; ++i) {
        int rn = wn * 64 + i * 16 + (l & 15);
        boff[i] = rn * 64 + ((((l >> 4) ^ ((rn >> 1) & 3))) << 4);
    }

    auto stage = [&](int ks, int buf) {
        const size_t kb = (size_t)ks * 64;
        char* dst = ldsc + buf * TS;
        const int soff = t * 16;
        const int srow = soff >> 6;
        const int slot = (soff >> 4) & 3;
        const size_t go = (size_t)srow * 1536 +
                          ((slot ^ ((srow >> 1) & 3)) << 4) + kb;
        // A tiles (4KB each): one load per thread
        __builtin_amdgcn_global_load_lds(GLB(gb[0] + go), LDS(dst + soff), 16, 0, 0);
        __builtin_amdgcn_global_load_lds(GLB(gb[1] + go), LDS(dst + SA + soff), 16, 0, 0);
        // B tiles (8KB each): two passes
#pragma unroll
        for (int p = 0; p < 2; ++p) {
            const int so2 = soff + p * 4096;
            const int sr2 = so2 >> 6;
            const int sl2 = (so2 >> 4) & 3;
            const size_t go2 = (size_t)sr2 * 1536 +
                               ((sl2 ^ ((sr2 >> 1) & 3)) << 4) + kb;
            __builtin_amdgcn_global_load_lds(GLB(gb[2] + go2), LDS(dst + 2 * SA + so2), 16, 0, 0);
            __builtin_amdgcn_global_load_lds(GLB(gb[3] + go2), LDS(dst + 2 * SA + SB + so2), 16, 0, 0);
        }
    };

    f32x4 acc[2][4] = {};

    stage(0, 0);

    for (int ks = 0; ks < 24; ++ks) {
        if (ks + 1 < 24) {
            stage(ks + 1, (ks + 1) & 1);
            VMCNT(6);
        } else {
            VMCNT(0);
        }
        __builtin_amdgcn_s_barrier();

        const char* cur = ldsc + (ks & 1) * TS;
        bf16x8 ah[2], al[2], bh[4], bl[4];
#pragma unroll
        for (int i = 0; i < 2; ++i) {
            ah[i] = *(const bf16x8*)(cur + aoff[i]);
            al[i] = *(const bf16x8*)(cur + SA + aoff[i]);
        }
#pragma unroll
        for (int i = 0; i < 4; ++i) {
            bh[i] = *(const bf16x8*)(cur + 2 * SA + boff[i]);
            bl[i] = *(const bf16x8*)(cur + 2 * SA + SB + boff[i]);
        }
        LGKM0();
        __builtin_amdgcn_sched_barrier(0);
        __builtin_amdgcn_s_barrier();

        __builtin_amdgcn_s_setprio(1);
#pragma unroll
        for (int i = 0; i < 2; ++i)
#pragma unroll
            for (int j = 0; j < 4; ++j) {
                acc[i][j] = __builtin_amdgcn_mfma_f32_16x16x32_bf16(ah[i], bh[j], acc[i][j], 0, 0, 0);
                acc[i][j] = __builtin_amdgcn_mfma_f32_16x16x32_bf16(ah[i], bl[j], acc[i][j], 0, 0, 0);
                acc[i][j] = __builtin_amdgcn_mfma_f32_16x16x32_bf16(al[i], bh[j], acc[i][j], 0, 0, 0);
            }
        __builtin_amdgcn_s_setprio(0);
    }

    const int mrow_base = m0 + wm * 32 + ((l >> 4) << 2);
    const int nin_base = n0 + wn * 64 + (l & 15);
#pragma unroll
    for (int j = 0; j < 4; ++j) {
        const int n_in = nin_base + j * 16;
        const float bv = b0[n_in];
#pragma unroll
        for (int i = 0; i < 2; ++i)
#pragma unroll
            for (int r = 0; r < 4; ++r) {
                const int m = mrow_base + i * 16 + r;
                o0[(size_t)m * 768 + n_in] = acc[i][j][r] + bv;
            }
    }
}

// ---------------------------------------------------------------------------
// Flash attention: 128 q-rows/block, 4 waves x 32 q. Each K/V fragment read
// feeds 2 MFMAs (q-groups). Double-buffered K/V, counted-vmcnt 2-barrier.
// LDS: Q/P 16K | K dbuf 2x8K | V dbuf 2x8K | pos dbuf 2x256B = 48.5KB
// ---------------------------------------------------------------------------
#define QPOFF  0
#define KOFF   16384
#define VOFF   32768
#define POSOFF 49152

__global__ __launch_bounds__(256) void attn_mfma(
    const ushort* __restrict__ q16, const ushort* __restrict__ k16,
    const ushort* __restrict__ vT16, const int* __restrict__ pos_pk,
    const float* __restrict__ rel_table,
    ushort* __restrict__ aoh, ushort* __restrict__ aol)
{
    __shared__ __align__(16) char lds[49664];

    const int t  = threadIdx.x;
    const int w  = t >> 6;
    const int l  = t & 63;
    const int bh = blockIdx.y;
    const int b  = bh / NHEADS;
    const int h  = bh - b * NHEADS;
    const int q0g = blockIdx.x * 128;

    const char* qb  = (const char*)(q16 + (size_t)bh * SEQ * HDIM);
    const char* kb  = (const char*)(k16 + (size_t)bh * SEQ * HDIM);
    const char* vtb = (const char*)(vT16 + (size_t)bh * HDIM * SEQ);

    const float t0 = rel_table[0 * NHEADS + h];
    const float t1 = rel_table[1 * NHEADS + h];
    const float t2 = rel_table[2 * NHEADS + h];
    const float t3 = rel_table[3 * NHEADS + h];

    const int o1 = t * 16, o2 = o1 + 4096;
    const int r1 = o1 >> 7, r2 = o2 >> 7;
    const int kq1 = o1 ^ ((r1 & 7) << 4);
    const int kq2 = o2 ^ ((r2 & 7) << 4);
    const int vs1 = r1 * 2048 + (((((o1 >> 4) & 7) ^ (r1 & 7))) << 4);
    const int vs2 = r2 * 2048 + (((((o2 >> 4) & 7) ^ (r2 & 7))) << 4);

    auto stage_kv = [&](int kt, int buf) {
        const int k0g = kt * 64;
        __builtin_amdgcn_global_load_lds(GLB(kb + (size_t)k0g * 128 + kq1),
                                         LDS(lds + KOFF + buf * 8192 + w * 1024), 16, 0, 0);
        __builtin_amdgcn_global_load_lds(GLB(kb + (size_t)k0g * 128 + kq2),
                                         LDS(lds + KOFF + buf * 8192 + w * 1024 + 4096), 16, 0, 0);
        __builtin_amdgcn_global_load_lds(GLB(vtb + (size_t)k0g * 2 + vs1),
                                         LDS(lds + VOFF + buf * 8192 + w * 1024), 16, 0, 0);
        __builtin_amdgcn_global_load_lds(GLB(vtb + (size_t)k0g * 2 + vs2),
                                         LDS(lds + VOFF + buf * 8192 + w * 1024 + 4096), 16, 0, 0);
        if (w == 0) {
            __builtin_amdgcn_global_load_lds(GLB(pos_pk + b * SEQ + k0g + l),
                                             LDS(lds + POSOFF + buf * 256), 4, 0, 0);
        }
    };

    // stage Q (16KB = 4 passes) + first K/V tile
#pragma unroll
    for (int p = 0; p < 4; ++p) {
        const int o = t * 16 + p * 4096;
        const int row = o >> 7;
        const int src = o ^ ((row & 7) << 4);
        __builtin_amdgcn_global_load_lds(GLB(qb + (size_t)q0g * 128 + src),
                                         LDS(lds + QPOFF + p * 4096 + w * 1024), 16, 0, 0);
    }
    stage_kv(0, 0);

    int pq[2];
    pq[0] = pos_pk[b * SEQ + q0g + w * 32 + (l & 15)];
    pq[1] = pos_pk[b * SEQ + q0g + w * 32 + 16 + (l & 15)];

    VMCNT(0);
    __builtin_amdgcn_s_barrier();

    bf16x8 qf[2][2];
#pragma unroll
    for (int qg = 0; qg < 2; ++qg)
#pragma unroll
        for (int ks = 0; ks < 2; ++ks) {
            const int qrow = w * 32 + qg * 16 + (l & 15);
            qf[qg][ks] = *(const bf16x8*)(lds + QPOFF + qrow * 128 +
                                          ((((l >> 4) + 4 * ks) ^ (qrow & 7)) << 4));
        }

    f32x4 pv[2][4] = {};
    float m_run[2] = {-1e30f, -1e30f};
    float l_run[2] = {0.0f, 0.0f};
    float alpha[2];

    const int prow = l & 15;
    const int pswz = (prow & 7) << 4;

    for (int kt = 0; kt < 16; ++kt) {
        const int cb = kt & 1;
        if (kt + 1 < 16) {
            stage_kv(kt + 1, cb ^ 1);
            if (w == 0) { VMCNT(5); } else { VMCNT(4); }
        } else {
            VMCNT(0);
        }
        __builtin_amdgcn_s_barrier();   // tile kt ready

        const char* kbuf = lds + KOFF + cb * 8192;
        const char* vbuf = lds + VOFF + cb * 8192;
        const char* pbuf = lds + POSOFF + cb * 256;

        // ---- QK^T swapped: each kf feeds both q-groups ----
        f32x4 sacc[2][4] = {};
        __builtin_amdgcn_s_setprio(1);
#pragma unroll
        for (int ks = 0; ks < 2; ++ks)
#pragma unroll
            for (int j = 0; j < 4; ++j) {
                const int krow = j * 16 + (l & 15);
                const bf16x8 kf = *(const bf16x8*)(kbuf + krow * 128 +
                                                   ((((l >> 4) + 4 * ks) ^ (krow & 7)) << 4));
                sacc[0][j] = __builtin_amdgcn_mfma_f32_16x16x32_bf16(kf, qf[0][ks], sacc[0][j], 0, 0, 0);
                sacc[1][j] = __builtin_amdgcn_mfma_f32_16x16x32_bf16(kf, qf[1][ks], sacc[1][j], 0, 0, 0);
            }
        __builtin_amdgcn_s_setprio(0);

        int4 pk4[4];
#pragma unroll
        for (int j = 0; j < 4; ++j)
            pk4[j] = *(const int4*)(pbuf + (l >> 4) * 16 + j * 64);

        // ---- softmax + P store per q-group ----
#pragma unroll
        for (int qg = 0; qg < 2; ++qg) {
            float sv[16];
#pragma unroll
            for (int j = 0; j < 4; ++j) {
                const int pkk[4] = {pk4[j].x, pk4[j].y, pk4[j].z, pk4[j].w};
#pragma unroll
                for (int r = 0; r < 4; ++r) {
                    const int dd = pq[qg] ^ pkk[r];
                    const float bs = ((dd & 0xFF00) == 0)
                                         ? (((dd & 0xFF) == 0) ? t3 : t1)
                                         : (((dd & 0xFF) == 0) ? t2 : t0);
                    sv[j * 4 + r] = sacc[qg][j][r] + bs;
                }
            }
            float pm = sv[0];
#pragma unroll
            for (int i = 1; i < 16; ++i) pm = fmaxf(pm, sv[i]);
            pm = fmaxf(pm, __shfl_xor(pm, 16));
            pm = fmaxf(pm, __shfl_xor(pm, 32));
            const float mnew = fmaxf(m_run[qg], pm);
            float psum = 0.0f;
#pragma unroll
            for (int i = 0; i < 16; ++i) {
                sv[i] = __expf(sv[i] - mnew);
                psum += sv[i];
            }
            psum += __shfl_xor(psum, 16);
            psum += __shfl_xor(psum, 32);
            alpha[qg] = __expf(m_run[qg] - mnew);
            l_run[qg] = l_run[qg] * alpha[qg] + psum;
            m_run[qg] = mnew;

#pragma unroll
            for (int r = 0; r < 4; ++r) {
                const float ar = __shfl(alpha[qg], (l >> 4) * 4 + r);
#pragma unroll
                for (int i = 0; i < 4; ++i) pv[qg][i][r] *= ar;
            }

            const int pwbase = QPOFF + w * 4096 + (qg * 16 + prow) * 128;
#pragma unroll
            for (int j = 0; j < 4; ++j)
#pragma unroll
                for (int p2 = 0; p2 < 2; ++p2) {
                    const uint u = bfr(sv[j * 4 + 2 * p2]) |
                                   (bfr(sv[j * 4 + 2 * p2 + 1]) << 16);
                    const int adr = pwbase + (((l >> 4) * 8 + 4 * p2 + 32 * j) ^ pswz);
                    *(uint*)(lds + adr) = u;
                }
        }

        // ---- PV: each vf feeds both q-groups ----
        __builtin_amdgcn_s_setprio(1);
#pragma unroll
        for (int ks = 0; ks < 2; ++ks) {
            const int pslot = (((l >> 4) + 4 * ks) << 4) ^ pswz;
            const bf16x8 pfA = *(const bf16x8*)(lds + QPOFF + w * 4096 + prow * 128 + pslot);
            const bf16x8 pfB = *(const bf16x8*)(lds + QPOFF + w * 4096 + (16 + prow) * 128 + pslot);
#pragma unroll
            for (int i = 0; i < 4; ++i) {
                const int vrow = i * 16 + (l & 15);
                const bf16x8 vf = *(const bf16x8*)(vbuf + vrow * 128 +
                                                   ((((l >> 4) + 4 * ks) ^ (vrow & 7)) << 4));
                pv[0][i] = __builtin_amdgcn_mfma_f32_16x16x32_bf16(pfA, vf, pv[0][i], 0, 0, 0);
                pv[1][i] = __builtin_amdgcn_mfma_f32_16x16x32_bf16(pfB, vf, pv[1][i], 0, 0, 0);
            }
        }
        __builtin_amdgcn_s_setprio(0);

        LGKM0();
        __builtin_amdgcn_sched_barrier(0);
        __builtin_amdgcn_s_barrier();   // all waves done with buf kt
    }

    // ---- epilogue ----
#pragma unroll
    for (int qg = 0; qg < 2; ++qg) {
        const float rinv = 1.0f / l_run[qg];
#pragma unroll
        for (int r = 0; r < 4; ++r) {
            const float inv = __shfl(rinv, (l >> 4) * 4 + r);
            const int mrow = b * SEQ + q0g + w * 32 + qg * 16 + (l >> 4) * 4 + r;
            const size_t base = (size_t)mrow * 768 + h * 64 + prow;
#pragma unroll
            for (int i = 0; i < 4; ++i) {
                const float o = pv[qg][i][r] * inv;
                const uint hu = bfr(o);
                const float hf = __uint_as_float(hu << 16);
                const uint lu = bfr(o - hf);
                aoh[base + 16 * i] = (ushort)hu;
                aol[base + 16 * i] = (ushort)lu;
            }
        }
    }
}

// ---------------------------------------------------------------------------
extern "C" void kernel_launch(void* const* d_in, const int* in_sizes, int n_in,
                              void* d_out, int out_size, void* d_ws, size_t ws_size,
                              hipStream_t stream)
{
    const float* hs      = (const float*)d_in[0];
    const int*   pos_row = (const int*)d_in[1];
    const int*   pos_col = (const int*)d_in[2];
    const float* q_w     = (const float*)d_in[3];
    const float* q_b     = (const float*)d_in[4];
    const float* k_w     = (const float*)d_in[5];
    const float* k_b     = (const float*)d_in[6];
    const float* v_w     = (const float*)d_in[7];
    const float* v_b     = (const float*)d_in[8];
    const float* o_w     = (const float*)d_in[9];
    const float* o_b     = (const float*)d_in[10];
    const float* rel_tab = (const float*)d_in[11];

    char* ws = (char*)d_ws;
    const size_t HS_N = (size_t)MTOT * EMB;
    const size_t W_N  = (size_t)EMB * EMB;
    ushort* hsh = (ushort*)ws;  ws += HS_N * 2;
    ushort* hsl = (ushort*)ws;  ws += HS_N * 2;
    ushort* wch = (ushort*)ws;  ws += 3 * W_N * 2;
    ushort* wcl = (ushort*)ws;  ws += 3 * W_N * 2;
    ushort* woh = (ushort*)ws;  ws += W_N * 2;
    ushort* wol = (ushort*)ws;  ws += W_N * 2;
    ushort* aoh = (ushort*)ws;  ws += HS_N * 2;
    ushort* aol = (ushort*)ws;  ws += HS_N * 2;
    ushort* q16 = (ushort*)ws;  ws += HS_N * 2;
    ushort* k16 = (ushort*)ws;  ws += HS_N * 2;
    ushort* vT16 = (ushort*)ws; ws += HS_N * 2;
    int* pos_pk = (int*)ws;     ws += MTOT * 4;

    split_all<<<5392, 256, 0, stream>>>(
        hs, q_w, k_w, v_w, o_w, pos_row, pos_col,
        hsh, hsl, wch, wcl, woh, wol, pos_pk);

    gemm_qkv<<<dim3(MTOT / 128, 2304 / 128), 512, 0, stream>>>(
        hsh, hsl, wch, wcl, q_b, k_b, v_b, q16, k16, vT16);

    attn_mfma<<<dim3(SEQ / 128, BATCH * NHEADS), 256, 0, stream>>>(
        q16, k16, vT16, pos_pk, rel_tab, aoh, aol);

    gemm_oproj<<<dim3(MTOT / 64, EMB / 128), 256, 0, stream>>>(
        aoh, aol, woh, wol, o_b, (float*)d_out);
}

// Round 12
// 202.884 us; speedup vs baseline: 1.0719x; 1.0719x over previous
//
#include <hip/hip_runtime.h>

#define NHEADS 12
#define HDIM   64
#define EMB    768
#define SEQ    1024
#define BATCH  4
#define MTOT   (BATCH * SEQ)

typedef __bf16 bf16x8 __attribute__((ext_vector_type(8)));
typedef float  f32x4  __attribute__((ext_vector_type(4)));

#define GLB(p) ((const __attribute__((address_space(1))) uint32_t*)(p))
#define LDS(p) ((__attribute__((address_space(3))) uint32_t*)(p))
#define VMCNT(n) asm volatile("s_waitcnt vmcnt(" #n ")" ::: "memory")
#define LGKM0()  asm volatile("s_waitcnt lgkmcnt(0)" ::: "memory")

#define LOG2E 1.4426950408889634f

__device__ __forceinline__ uint bfr(float f) {  // f32 -> bf16 bits, RNE
    uint u = __float_as_uint(f);
    return (u + 0x7fffu + ((u >> 16) & 1u)) >> 16;
}
__device__ __forceinline__ float fmax3(float a, float b, float c) {
    return fmaxf(fmaxf(a, b), c);   // clang fuses to v_max3_f32
}
__device__ __forceinline__ float fexp2(float x) {
    return __builtin_amdgcn_exp2f(x);   // bare v_exp_f32
}

// ---------------------------------------------------------------------------
// One launch: split hs + 4 weights to bf16 hi/lo, and pack pos_row/col.
// ---------------------------------------------------------------------------
__global__ __launch_bounds__(256) void split_all(
    const float* __restrict__ hs,
    const float* __restrict__ w0, const float* __restrict__ w1,
    const float* __restrict__ w2, const float* __restrict__ w3,
    const int* __restrict__ pos_row, const int* __restrict__ pos_col,
    ushort* __restrict__ hsh, ushort* __restrict__ hsl,
    ushort* __restrict__ wch, ushort* __restrict__ wcl,
    ushort* __restrict__ woh, ushort* __restrict__ wol,
    int* __restrict__ pos_pk)
{
    const int bx = blockIdx.x;
    if (bx >= 5376) {
        int i = (bx - 5376) * 256 + threadIdx.x;
        pos_pk[i] = (pos_row[i] << 8) | pos_col[i];
        return;
    }
    const float* src;
    ushort *hi, *lo;
    int i;
    if (bx < 3072) {
        src = hs; hi = hsh; lo = hsl;
        i = bx * 256 + threadIdx.x;
    } else {
        const int y = (bx - 3072) / 576;
        const int r = (bx - 3072) - y * 576;
        src = (y == 0) ? w0 : (y == 1) ? w1 : (y == 2) ? w2 : w3;
        hi = (y < 3) ? (wch + (size_t)y * (EMB * EMB)) : woh;
        lo = (y < 3) ? (wcl + (size_t)y * (EMB * EMB)) : wol;
        i = r * 256 + threadIdx.x;
    }
    float4 v = ((const float4*)src)[i];
    float f[4] = {v.x, v.y, v.z, v.w};
    ushort hh[4], ll[4];
#pragma unroll
    for (int j = 0; j < 4; ++j) {
        uint h = bfr(f[j]);
        float hf = __uint_as_float(h << 16);
        ll[j] = (ushort)bfr(f[j] - hf);
        hh[j] = (ushort)h;
    }
    ushort4 hv = {hh[0], hh[1], hh[2], hh[3]};
    ushort4 lv = {ll[0], ll[1], ll[2], ll[3]};
    ((ushort4*)hi)[i] = hv;
    ((ushort4*)lo)[i] = lv;
}

// ---------------------------------------------------------------------------
// QKV GEMM: round-7 measured-best: 128x128 tile, BK=32, 8 waves of 64x32,
// counted-vmcnt 2-barrier schedule with lgkm pin before MFMA.
// q scaled by 0.125*log2e (attn softmax runs in exp2 domain).
// ---------------------------------------------------------------------------
__global__ __launch_bounds__(512) void gemm_qkv(
    const ushort* __restrict__ Ah, const ushort* __restrict__ Al,
    const ushort* __restrict__ Wh, const ushort* __restrict__ Wl,
    const float* __restrict__ b0, const float* __restrict__ b1,
    const float* __restrict__ b2,
    ushort* __restrict__ q16, ushort* __restrict__ k16,
    ushort* __restrict__ vT16)
{
    constexpr int TS = 32768;  // [Ah 8K][Al 8K][Wh 8K][Wl 8K]
    __shared__ __align__(16) char ldsc[2 * TS];

    const int t  = threadIdx.x;
    const int w  = t >> 6;
    const int l  = t & 63;
    const int m0 = blockIdx.x * 128;
    const int n0 = blockIdx.y * 128;
    const int wm = w >> 2;   // 0..1
    const int wn = w & 3;    // 0..3

    const char* gb[4] = {
        (const char*)Ah + (size_t)m0 * 1536,
        (const char*)Al + (size_t)m0 * 1536,
        (const char*)Wh + (size_t)n0 * 1536,
        (const char*)Wl + (size_t)n0 * 1536};

    int aoff[4], boff[2];
#pragma unroll
    for (int i = 0; i < 4; ++i) {
        int row = wm * 64 + i * 16 + (l & 15);
        aoff[i] = row * 64 + ((((l >> 4) ^ ((row >> 1) & 3))) << 4);
    }
#pragma unroll
    for (int j = 0; j < 2; ++j) {
        int rn = wn * 32 + j * 16 + (l & 15);
        boff[j] = rn * 64 + ((((l >> 4) ^ ((rn >> 1) & 3))) << 4);
    }

    auto stage = [&](int ks, int buf) {
        const size_t kb = (size_t)ks * 64;
        char* dst = ldsc + buf * TS;
        const int soff = t * 16;
        const int srow = soff >> 6;
        const int slot = (soff >> 4) & 3;
        const size_t go = (size_t)srow * 1536 +
                          ((slot ^ ((srow >> 1) & 3)) << 4) + kb;
#pragma unroll
        for (int tt = 0; tt < 4; ++tt)
            __builtin_amdgcn_global_load_lds(GLB(gb[tt] + go),
                                             LDS(dst + tt * 8192 + soff), 16, 0, 0);
    };

    f32x4 acc[4][2] = {};

    stage(0, 0);

    for (int ks = 0; ks < 24; ++ks) {
        if (ks + 1 < 24) {
            stage(ks + 1, (ks + 1) & 1);
            VMCNT(4);
        } else {
            VMCNT(0);
        }
        __builtin_amdgcn_s_barrier();

        const char* cur = ldsc + (ks & 1) * TS;
        bf16x8 ah[4], al[4], bh[2], bl[2];
#pragma unroll
        for (int i = 0; i < 4; ++i) {
            ah[i] = *(const bf16x8*)(cur + aoff[i]);
            al[i] = *(const bf16x8*)(cur + 8192 + aoff[i]);
        }
#pragma unroll
        for (int j = 0; j < 2; ++j) {
            bh[j] = *(const bf16x8*)(cur + 16384 + boff[j]);
            bl[j] = *(const bf16x8*)(cur + 24576 + boff[j]);
        }
        LGKM0();
        __builtin_amdgcn_sched_barrier(0);
        __builtin_amdgcn_s_barrier();

        __builtin_amdgcn_s_setprio(1);
#pragma unroll
        for (int i = 0; i < 4; ++i)
#pragma unroll
            for (int j = 0; j < 2; ++j) {
                acc[i][j] = __builtin_amdgcn_mfma_f32_16x16x32_bf16(ah[i], bh[j], acc[i][j], 0, 0, 0);
                acc[i][j] = __builtin_amdgcn_mfma_f32_16x16x32_bf16(ah[i], bl[j], acc[i][j], 0, 0, 0);
                acc[i][j] = __builtin_amdgcn_mfma_f32_16x16x32_bf16(al[i], bh[j], acc[i][j], 0, 0, 0);
            }
        __builtin_amdgcn_s_setprio(0);
    }

    const int mrow_base = m0 + wm * 64 + ((l >> 4) << 2);
    const int which = (n0 >= 1536) ? 2 : (n0 >= 768 ? 1 : 0);
    const int nin_base = n0 - which * 768 + wn * 32 + (l & 15);

    if (which == 2) {
#pragma unroll
        for (int j = 0; j < 2; ++j) {
            const int n_in = nin_base + j * 16;
            const float bv = b2[n_in];
            const int h = n_in >> 6, d = n_in & 63;
#pragma unroll
            for (int i = 0; i < 4; ++i) {
                const int m = mrow_base + i * 16;
                const int bb = m >> 10, s = m & 1023;
                ushort4 pk = {(ushort)bfr(acc[i][j][0] + bv),
                              (ushort)bfr(acc[i][j][1] + bv),
                              (ushort)bfr(acc[i][j][2] + bv),
                              (ushort)bfr(acc[i][j][3] + bv)};
                *(ushort4*)(vT16 + (size_t)((bb * NHEADS + h) * HDIM + d) * SEQ + s) = pk;
            }
        }
    } else {
        ushort* op = (which == 0) ? q16 : k16;
        const float* bpt = (which == 0) ? b0 : b1;
        const float scale = (which == 0) ? (0.125f * LOG2E) : 1.0f;
#pragma unroll
        for (int j = 0; j < 2; ++j) {
            const int n_in = nin_base + j * 16;
            const float bv = bpt[n_in];
            const int h = n_in >> 6, d = n_in & 63;
#pragma unroll
            for (int i = 0; i < 4; ++i)
#pragma unroll
                for (int r = 0; r < 4; ++r) {
                    const int m = mrow_base + i * 16 + r;
                    const int bb = m >> 10, s = m & 1023;
                    op[(size_t)((bb * NHEADS + h) * SEQ + s) * HDIM + d] =
                        (ushort)bfr((acc[i][j][r] + bv) * scale);
                }
        }
    }
}

// ---------------------------------------------------------------------------
// o-projection: round-7 form: BM=64 x 128, 8 waves of 32x32, counted-vmcnt.
// ---------------------------------------------------------------------------
__global__ __launch_bounds__(512) void gemm_oproj(
    const ushort* __restrict__ Ah, const ushort* __restrict__ Al,
    const ushort* __restrict__ Wh, const ushort* __restrict__ Wl,
    const float* __restrict__ b0, float* __restrict__ o0)
{
    constexpr int SA = 4096;
    constexpr int SB = 8192;
    constexpr int TS = 2 * SA + 2 * SB;  // 24576
    __shared__ __align__(16) char ldsc[2 * TS];

    const int t  = threadIdx.x;
    const int w  = t >> 6;
    const int l  = t & 63;
    const int m0 = blockIdx.x * 64;
    const int n0 = blockIdx.y * 128;
    const int wm = w >> 2;
    const int wn = w & 3;

    const char* gb[4] = {
        (const char*)Ah + (size_t)m0 * 1536,
        (const char*)Al + (size_t)m0 * 1536,
        (const char*)Wh + (size_t)n0 * 1536,
        (const char*)Wl + (size_t)n0 * 1536};

    int aoff[2], boff[2];
#pragma unroll
    for (int i = 0; i < 2; ++i) {
        int row = wm * 32 + i * 16 + (l & 15);
        aoff[i] = row * 64 + ((((l >> 4) ^ ((row >> 1) & 3))) << 4);
    }
#pragma unroll
    for (int i = 0; i < 2; ++i) {
        int rn = wn * 32 + i * 16 + (l & 15);
        boff[i] = rn * 64 + ((((l >> 4) ^ ((rn >> 1) & 3))) << 4);
    }

    auto stage = [&](int ks, int buf) {
        const size_t kb = (size_t)ks * 64;
        char* dst = ldsc + buf * TS;
        const int soff = t * 16;
        const int srow = soff >> 6;
        const int slot = (soff >> 4) & 3;
        const size_t go = (size_t)srow * 1536 +
                          ((slot ^ ((srow >> 1) & 3)) << 4) + kb;
        if (soff < SA) {  // waves 0-3 only
            __builtin_amdgcn_global_load_lds(GLB(gb[0] + go), LDS(dst + soff), 16, 0, 0);
            __builtin_amdgcn_global_load_lds(GLB(gb[1] + go), LDS(dst + SA + soff), 16, 0, 0);
        }
        __builtin_amdgcn_global_load_lds(GLB(gb[2] + go), LDS(dst + 2 * SA + soff), 16, 0, 0);
        __builtin_amdgcn_global_load_lds(GLB(gb[3] + go), LDS(dst + 2 * SA + SB + soff), 16, 0, 0);
    };

    f32x4 acc[2][2] = {};

    stage(0, 0);

    for (int ks = 0; ks < 24; ++ks) {
        if (ks + 1 < 24) {
            stage(ks + 1, (ks + 1) & 1);
            if (w < 4) { VMCNT(4); } else { VMCNT(2); }
        } else {
            VMCNT(0);
        }
        __builtin_amdgcn_s_barrier();

        const char* cur = ldsc + (ks & 1) * TS;
        bf16x8 ah[2], al[2], bh[2], bl[2];
#pragma unroll
        for (int i = 0; i < 2; ++i) {
            ah[i] = *(const bf16x8*)(cur + aoff[i]);
            al[i] = *(const bf16x8*)(cur + SA + aoff[i]);
        }
#pragma unroll
        for (int i = 0; i < 2; ++i) {
            bh[i] = *(const bf16x8*)(cur + 2 * SA + boff[i]);
            bl[i] = *(const bf16x8*)(cur + 2 * SA + SB + boff[i]);
        }
        LGKM0();
        __builtin_amdgcn_sched_barrier(0);
        __builtin_amdgcn_s_barrier();

        __builtin_amdgcn_s_setprio(1);
#pragma unroll
        for (int i = 0; i < 2; ++i)
#pragma unroll
            for (int j = 0; j < 2; ++j) {
                acc[i][j] = __builtin_amdgcn_mfma_f32_16x16x32_bf16(ah[i], bh[j], acc[i][j], 0, 0, 0);
                acc[i][j] = __builtin_amdgcn_mfma_f32_16x16x32_bf16(ah[i], bl[j], acc[i][j], 0, 0, 0);
                acc[i][j] = __builtin_amdgcn_mfma_f32_16x16x32_bf16(al[i], bh[j], acc[i][j], 0, 0, 0);
            }
        __builtin_amdgcn_s_setprio(0);
    }

    const int mrow_base = m0 + wm * 32 + ((l >> 4) << 2);
    const int nin_base = n0 + wn * 32 + (l & 15);
#pragma unroll
    for (int j = 0; j < 2; ++j) {
        const int n_in = nin_base + j * 16;
        const float bv = b0[n_in];
#pragma unroll
        for (int i = 0; i < 2; ++i)
#pragma unroll
            for (int r = 0; r < 4; ++r) {
                const int m = mrow_base + i * 16 + r;
                o0[(size_t)m * 768 + n_in] = acc[i][j][r] + bv;
            }
    }
}

// ---------------------------------------------------------------------------
// Flash attention (round-7 structure: 64 q/block, 4 waves, 768 blocks) with
// VALU diet: exp2 domain, v_max3 tree max, paired-tree sum, cvt_pk P-pack.
// ---------------------------------------------------------------------------
#define QPOFF  0
#define KOFF   8192
#define VOFF   24576
#define POSOFF 40960

__global__ __launch_bounds__(256) void attn_mfma(
    const ushort* __restrict__ q16, const ushort* __restrict__ k16,
    const ushort* __restrict__ vT16, const int* __restrict__ pos_pk,
    const float* __restrict__ rel_table,
    ushort* __restrict__ aoh, ushort* __restrict__ aol)
{
    __shared__ __align__(16) char lds[41472];

    const int t  = threadIdx.x;
    const int w  = t >> 6;
    const int l  = t & 63;
    const int bh = blockIdx.y;
    const int b  = bh / NHEADS;
    const int h  = bh - b * NHEADS;
    const int q0g = blockIdx.x * 64;

    const char* qb  = (const char*)(q16 + (size_t)bh * SEQ * HDIM);
    const char* kb  = (const char*)(k16 + (size_t)bh * SEQ * HDIM);
    const char* vtb = (const char*)(vT16 + (size_t)bh * HDIM * SEQ);

    // bias tables in log2 domain (scores already carry log2e via q scale)
    const float t0 = rel_table[0 * NHEADS + h] * LOG2E;
    const float t1 = rel_table[1 * NHEADS + h] * LOG2E;
    const float t2 = rel_table[2 * NHEADS + h] * LOG2E;
    const float t3 = rel_table[3 * NHEADS + h] * LOG2E;

    const int o1 = t * 16, o2 = o1 + 4096;
    const int r1 = o1 >> 7, r2 = o2 >> 7;
    const int kq1 = o1 ^ ((r1 & 7) << 4);
    const int kq2 = o2 ^ ((r2 & 7) << 4);
    const int vs1 = r1 * 2048 + (((((o1 >> 4) & 7) ^ (r1 & 7))) << 4);
    const int vs2 = r2 * 2048 + (((((o2 >> 4) & 7) ^ (r2 & 7))) << 4);

    auto stage_kv = [&](int kt, int buf) {
        const int k0g = kt * 64;
        __builtin_amdgcn_global_load_lds(GLB(kb + (size_t)k0g * 128 + kq1),
                                         LDS(lds + KOFF + buf * 8192 + w * 1024), 16, 0, 0);
        __builtin_amdgcn_global_load_lds(GLB(kb + (size_t)k0g * 128 + kq2),
                                         LDS(lds + KOFF + buf * 8192 + w * 1024 + 4096), 16, 0, 0);
        __builtin_amdgcn_global_load_lds(GLB(vtb + (size_t)k0g * 2 + vs1),
                                         LDS(lds + VOFF + buf * 8192 + w * 1024), 16, 0, 0);
        __builtin_amdgcn_global_load_lds(GLB(vtb + (size_t)k0g * 2 + vs2),
                                         LDS(lds + VOFF + buf * 8192 + w * 1024 + 4096), 16, 0, 0);
        if (w == 0) {
            __builtin_amdgcn_global_load_lds(GLB(pos_pk + b * SEQ + k0g + l),
                                             LDS(lds + POSOFF + buf * 256), 4, 0, 0);
        }
    };

    __builtin_amdgcn_global_load_lds(GLB(qb + (size_t)q0g * 128 + kq1),
                                     LDS(lds + QPOFF + w * 1024), 16, 0, 0);
    __builtin_amdgcn_global_load_lds(GLB(qb + (size_t)q0g * 128 + kq2),
                                     LDS(lds + QPOFF + w * 1024 + 4096), 16, 0, 0);
    stage_kv(0, 0);

    const int qrow_g = q0g + w * 16 + (l & 15);
    const int pq = pos_pk[b * SEQ + qrow_g];

    VMCNT(0);
    __builtin_amdgcn_s_barrier();

    bf16x8 qf[2];
    const int qrl = w * 16 + (l & 15);
#pragma unroll
    for (int ks = 0; ks < 2; ++ks)
        qf[ks] = *(const bf16x8*)(lds + QPOFF + qrl * 128 +
                                  ((((l >> 4) + 4 * ks) ^ (qrl & 7)) << 4));

    f32x4 pv[4] = {};
    float m_run = -1e30f, l_run = 0.0f;

    const int prow = l & 15;
    const int pswz = (prow & 7) << 4;
    const int pwbase = QPOFF + w * 2048 + prow * 128;

    for (int kt = 0; kt < 16; ++kt) {
        const int cb = kt & 1;
        if (kt + 1 < 16) {
            stage_kv(kt + 1, cb ^ 1);
            if (w == 0) { VMCNT(5); } else { VMCNT(4); }
        } else {
            VMCNT(0);
        }
        __builtin_amdgcn_s_barrier();   // tile kt ready

        const char* kbuf = lds + KOFF + cb * 8192;
        const char* vbuf = lds + VOFF + cb * 8192;
        const char* pbuf = lds + POSOFF + cb * 256;

        f32x4 sacc[4] = {};
        __builtin_amdgcn_s_setprio(1);
#pragma unroll
        for (int ks = 0; ks < 2; ++ks) {
            const bf16x8 qq = qf[ks];
#pragma unroll
            for (int j = 0; j < 4; ++j) {
                const int krow = j * 16 + (l & 15);
                const bf16x8 kf = *(const bf16x8*)(kbuf + krow * 128 +
                                                   ((((l >> 4) + 4 * ks) ^ (krow & 7)) << 4));
                sacc[j] = __builtin_amdgcn_mfma_f32_16x16x32_bf16(kf, qq, sacc[j], 0, 0, 0);
            }
        }
        __builtin_amdgcn_s_setprio(0);

        int4 pk4[4];
#pragma unroll
        for (int j = 0; j < 4; ++j)
            pk4[j] = *(const int4*)(pbuf + (l >> 4) * 16 + j * 64);

        float sv[16];
#pragma unroll
        for (int j = 0; j < 4; ++j) {
            const int pkk[4] = {pk4[j].x, pk4[j].y, pk4[j].z, pk4[j].w};
#pragma unroll
            for (int r = 0; r < 4; ++r) {
                const int dd = pq ^ pkk[r];
                const float bs = ((dd & 0xFF00) == 0)
                                     ? (((dd & 0xFF) == 0) ? t3 : t1)
                                     : (((dd & 0xFF) == 0) ? t2 : t0);
                sv[j * 4 + r] = sacc[j][r] + bs;
            }
        }

        // max via v_max3 tree (depth 3)
        float mA = fmax3(sv[0], sv[1], sv[2]);
        float mB = fmax3(sv[3], sv[4], sv[5]);
        float mC = fmax3(sv[6], sv[7], sv[8]);
        float mD = fmax3(sv[9], sv[10], sv[11]);
        float mE = fmax3(sv[12], sv[13], sv[14]);
        float pm = fmax3(fmax3(mA, mB, mC), mD, fmaxf(mE, sv[15]));
        pm = fmaxf(pm, __shfl_xor(pm, 16));
        pm = fmaxf(pm, __shfl_xor(pm, 32));
        const float mnew = fmaxf(m_run, pm);

        // exp2 + paired-tree sum (depth 4)
#pragma unroll
        for (int i = 0; i < 16; ++i) sv[i] = fexp2(sv[i] - mnew);
        float s01 = (sv[0] + sv[1]) + (sv[2] + sv[3]);
        float s23 = (sv[4] + sv[5]) + (sv[6] + sv[7]);
        float s45 = (sv[8] + sv[9]) + (sv[10] + sv[11]);
        float s67 = (sv[12] + sv[13]) + (sv[14] + sv[15]);
        float psum = (s01 + s23) + (s45 + s67);
        psum += __shfl_xor(psum, 16);
        psum += __shfl_xor(psum, 32);
        const float alpha = fexp2(m_run - mnew);
        l_run = l_run * alpha + psum;
        m_run = mnew;

#pragma unroll
        for (int r = 0; r < 4; ++r) {
            const float ar = __shfl(alpha, (l >> 4) * 4 + r);
#pragma unroll
            for (int i = 0; i < 4; ++i) pv[i][r] *= ar;
        }

        // P -> bf16 via v_cvt_pk_bf16_f32 (1 op per pair)
#pragma unroll
        for (int j = 0; j < 4; ++j)
#pragma unroll
            for (int p2 = 0; p2 < 2; ++p2) {
                uint u;
                asm("v_cvt_pk_bf16_f32 %0, %1, %2"
                    : "=v"(u) : "v"(sv[j * 4 + 2 * p2]), "v"(sv[j * 4 + 2 * p2 + 1]));
                const int adr = pwbase + (((l >> 4) * 8 + 4 * p2 + 32 * j) ^ pswz);
                *(uint*)(lds + adr) = u;
            }

        __builtin_amdgcn_s_setprio(1);
#pragma unroll
        for (int ks = 0; ks < 2; ++ks) {
            const bf16x8 pf = *(const bf16x8*)(lds + pwbase +
                                               ((((l >> 4) + 4 * ks) << 4) ^ pswz));
#pragma unroll
            for (int i = 0; i < 4; ++i) {
                const int vrow = i * 16 + (l & 15);
                const bf16x8 vf = *(const bf16x8*)(vbuf + vrow * 128 +
                                                   ((((l >> 4) + 4 * ks) ^ (vrow & 7)) << 4));
                pv[i] = __builtin_amdgcn_mfma_f32_16x16x32_bf16(pf, vf, pv[i], 0, 0, 0);
            }
        }
        __builtin_amdgcn_s_setprio(0);

        LGKM0();
        __builtin_amdgcn_sched_barrier(0);
        __builtin_amdgcn_s_barrier();   // all waves done with buf kt
    }

    const float rinv = 1.0f / l_run;
#pragma unroll
    for (int r = 0; r < 4; ++r) {
        const float inv = __shfl(rinv, (l >> 4) * 4 + r);
        const int mrow = b * SEQ + q0g + w * 16 + (l >> 4) * 4 + r;
        const size_t base = (size_t)mrow * 768 + h * 64 + prow;
#pragma unroll
        for (int i = 0; i < 4; ++i) {
            const float o = pv[i][r] * inv;
            const uint hu = bfr(o);
            const float hf = __uint_as_float(hu << 16);
            const uint lu = bfr(o - hf);
            aoh[base + 16 * i] = (ushort)hu;
            aol[base + 16 * i] = (ushort)lu;
        }
    }
}

// ---------------------------------------------------------------------------
extern "C" void kernel_launch(void* const* d_in, const int* in_sizes, int n_in,
                              void* d_out, int out_size, void* d_ws, size_t ws_size,
                              hipStream_t stream)
{
    const float* hs      = (const float*)d_in[0];
    const int*   pos_row = (const int*)d_in[1];
    const int*   pos_col = (const int*)d_in[2];
    const float* q_w     = (const float*)d_in[3];
    const float* q_b     = (const float*)d_in[4];
    const float* k_w     = (const float*)d_in[5];
    const float* k_b     = (const float*)d_in[6];
    const float* v_w     = (const float*)d_in[7];
    const float* v_b     = (const float*)d_in[8];
    const float* o_w     = (const float*)d_in[9];
    const float* o_b     = (const float*)d_in[10];
    const float* rel_tab = (const float*)d_in[11];

    char* ws = (char*)d_ws;
    const size_t HS_N = (size_t)MTOT * EMB;
    const size_t W_N  = (size_t)EMB * EMB;
    ushort* hsh = (ushort*)ws;  ws += HS_N * 2;
    ushort* hsl = (ushort*)ws;  ws += HS_N * 2;
    ushort* wch = (ushort*)ws;  ws += 3 * W_N * 2;
    ushort* wcl = (ushort*)ws;  ws += 3 * W_N * 2;
    ushort* woh = (ushort*)ws;  ws += W_N * 2;
    ushort* wol = (ushort*)ws;  ws += W_N * 2;
    ushort* aoh = (ushort*)ws;  ws += HS_N * 2;
    ushort* aol = (ushort*)ws;  ws += HS_N * 2;
    ushort* q16 = (ushort*)ws;  ws += HS_N * 2;
    ushort* k16 = (ushort*)ws;  ws += HS_N * 2;
    ushort* vT16 = (ushort*)ws; ws += HS_N * 2;
    int* pos_pk = (int*)ws;     ws += MTOT * 4;

    split_all<<<5392, 256, 0, stream>>>(
        hs, q_w, k_w, v_w, o_w, pos_row, pos_col,
        hsh, hsl, wch, wcl, woh, wol, pos_pk);

    gemm_qkv<<<dim3(MTOT / 128, 2304 / 128), 512, 0, stream>>>(
        hsh, hsl, wch, wcl, q_b, k_b, v_b, q16, k16, vT16);

    attn_mfma<<<dim3(SEQ / 64, BATCH * NHEADS), 256, 0, stream>>>(
        q16, k16, vT16, pos_pk, rel_tab, aoh, aol);

    gemm_oproj<<<dim3(MTOT / 64, EMB / 128), 512, 0, stream>>>(
        aoh, aol, woh, wol, o_b, (float*)d_out);
}